// Round 1
// baseline (90.750 us; speedup 1.0000x reference)
//
#include <hip/hip_runtime.h>

constexpr int DSZ = 192, HSZ = 192, WSZ = 192, BSZ = 2;
constexpr int ROWS = BSZ * DSZ * HSZ;      // 73728 rows of 192 floats
constexpr int NBLOCKS = 2304;              // 32 rows per block
constexpr int ROWS_PER_BLOCK = ROWS / NBLOCKS;
constexpr float SMOOTH = 1e-5f;

// gradient magnitude of the 3x3x3 central-diff stencil (zero padding)
__device__ __forceinline__ float bmag(const float* __restrict__ x,
                                      size_t idx, int d, int h, int w) {
    const size_t sd = (size_t)HSZ * WSZ;
    float xd0 = (d > 0)       ? x[idx - sd]  : 0.f;
    float xd1 = (d < DSZ - 1) ? x[idx + sd]  : 0.f;
    float xh0 = (h > 0)       ? x[idx - WSZ] : 0.f;
    float xh1 = (h < HSZ - 1) ? x[idx + WSZ] : 0.f;
    float xw0 = (w > 0)       ? x[idx - 1]   : 0.f;
    float xw1 = (w < WSZ - 1) ? x[idx + 1]   : 0.f;
    float gx = xd1 - xd0;
    float gy = xh1 - xh0;
    float gz = xw1 - xw0;
    return sqrtf(fmaf(gx, gx, fmaf(gy, gy, fmaf(gz, gz, SMOOTH))));
}

__global__ __launch_bounds__(192)
void bl_main(const float* __restrict__ pred,
             const float* __restrict__ target,
             double* __restrict__ acc) {
    const int w = threadIdx.x;          // 0..191
    float s_pt = 0.f, s_p = 0.f, s_t = 0.f;

    const int row0 = blockIdx.x * ROWS_PER_BLOCK;
    for (int r = 0; r < ROWS_PER_BLOCK; ++r) {
        const int row = row0 + r;
        const int h  = row % HSZ;
        const int bd = row / HSZ;
        const int d  = bd % DSZ;
        const size_t idx = (size_t)row * WSZ + w;
        const float pb = bmag(pred,   idx, d, h, w);
        const float tb = bmag(target, idx, d, h, w);
        s_pt = fmaf(pb, tb, s_pt);
        s_p += pb;
        s_t += tb;
    }

    // wave (64-lane) reduction
    #pragma unroll
    for (int off = 32; off; off >>= 1) {
        s_pt += __shfl_down(s_pt, off);
        s_p  += __shfl_down(s_p,  off);
        s_t  += __shfl_down(s_t,  off);
    }

    __shared__ float red[3][4];   // 3 waves x {pt,p,t}
    const int lane = threadIdx.x & 63;
    const int wid  = threadIdx.x >> 6;
    if (lane == 0) {
        red[wid][0] = s_pt;
        red[wid][1] = s_p;
        red[wid][2] = s_t;
    }
    __syncthreads();
    if (threadIdx.x == 0) {
        double a_pt = (double)red[0][0] + (double)red[1][0] + (double)red[2][0];
        double a_p  = (double)red[0][1] + (double)red[1][1] + (double)red[2][1];
        double a_t  = (double)red[0][2] + (double)red[1][2] + (double)red[2][2];
        // slots padded to separate cachelines (8 doubles = 64B apart)
        atomicAdd(&acc[0],  a_pt);
        atomicAdd(&acc[8],  a_p);
        atomicAdd(&acc[16], a_t);
    }
}

__global__ void bl_final(const double* __restrict__ acc, float* __restrict__ out) {
    const double I = acc[0];
    const double P = acc[8];
    const double T = acc[16];
    const double dice = (2.0 * I + 1e-5) / (P + T + 1e-5);
    out[0] = (float)(1.0 - dice);
}

extern "C" void kernel_launch(void* const* d_in, const int* in_sizes, int n_in,
                              void* d_out, int out_size, void* d_ws, size_t ws_size,
                              hipStream_t stream) {
    const float* pred   = (const float*)d_in[0];
    const float* target = (const float*)d_in[1];
    double* acc = (double*)d_ws;

    hipMemsetAsync(d_ws, 0, 17 * sizeof(double), stream);
    bl_main<<<NBLOCKS, 192, 0, stream>>>(pred, target, acc);
    bl_final<<<1, 1, 0, stream>>>(acc, (float*)d_out);
}

// Round 2
// 74.772 us; speedup vs baseline: 1.2137x; 1.2137x over previous
//
#include <hip/hip_runtime.h>

constexpr int DSZ = 192, HSZ = 192, WSZ = 192, BSZ = 2;
constexpr int WQ = WSZ / 4;                         // 48 float4 per row
constexpr int TOTAL_FQ = BSZ * DSZ * HSZ * WQ;      // 3,538,944 float4s
constexpr int NBLOCKS = 2304;                       // % 8 == 0 for XCD swizzle
constexpr int TPB = 256;
constexpr int ITERS = TOTAL_FQ / (NBLOCKS * TPB);   // 6
constexpr float SMOOTH = 1e-5f;

__device__ __forceinline__ float4 ld4(const float* __restrict__ p) {
    return *reinterpret_cast<const float4*>(p);
}

// boundary magnitude for 4 consecutive w at float-index `base`
__device__ __forceinline__ void bmag4(const float* __restrict__ x, size_t base,
                                      int d, int h, int wq, float o[4]) {
    const size_t sd = (size_t)HSZ * WSZ;
    const float4 z = make_float4(0.f, 0.f, 0.f, 0.f);
    float4 c  = ld4(x + base);
    float4 d0 = (d > 0)       ? ld4(x + base - sd)  : z;
    float4 d1 = (d < DSZ - 1) ? ld4(x + base + sd)  : z;
    float4 h0 = (h > 0)       ? ld4(x + base - WSZ) : z;
    float4 h1 = (h < HSZ - 1) ? ld4(x + base + WSZ) : z;
    float wl  = (wq > 0)      ? x[base - 1] : 0.f;
    float wr  = (wq < WQ - 1) ? x[base + 4] : 0.f;

    float gx0 = d1.x - d0.x, gx1 = d1.y - d0.y, gx2 = d1.z - d0.z, gx3 = d1.w - d0.w;
    float gy0 = h1.x - h0.x, gy1 = h1.y - h0.y, gy2 = h1.z - h0.z, gy3 = h1.w - h0.w;
    float gz0 = c.y - wl,    gz1 = c.z - c.x,   gz2 = c.w - c.y,   gz3 = wr - c.z;

    o[0] = sqrtf(fmaf(gx0, gx0, fmaf(gy0, gy0, fmaf(gz0, gz0, SMOOTH))));
    o[1] = sqrtf(fmaf(gx1, gx1, fmaf(gy1, gy1, fmaf(gz1, gz1, SMOOTH))));
    o[2] = sqrtf(fmaf(gx2, gx2, fmaf(gy2, gy2, fmaf(gz2, gz2, SMOOTH))));
    o[3] = sqrtf(fmaf(gx3, gx3, fmaf(gy3, gy3, fmaf(gz3, gz3, SMOOTH))));
}

__global__ __launch_bounds__(TPB)
void bl_main(const float* __restrict__ pred,
             const float* __restrict__ target,
             double* __restrict__ acc) {
    // XCD-chunked swizzle: XCD x gets contiguous chunks [x*288, (x+1)*288)
    const int swz = (blockIdx.x & 7) * (NBLOCKS / 8) + (blockIdx.x >> 3);
    const int fq_base = swz * (TPB * ITERS) + threadIdx.x;

    float s_pt = 0.f, s_p = 0.f, s_t = 0.f;

    #pragma unroll
    for (int i = 0; i < ITERS; ++i) {
        const int fq  = fq_base + i * TPB;
        const int wq  = fq % WQ;
        const int row = fq / WQ;
        const int h   = row % HSZ;
        const int d   = (row / HSZ) % DSZ;
        const size_t base = (size_t)fq * 4;

        float pb[4], tb[4];
        bmag4(pred,   base, d, h, wq, pb);
        bmag4(target, base, d, h, wq, tb);

        #pragma unroll
        for (int j = 0; j < 4; ++j) {
            s_pt = fmaf(pb[j], tb[j], s_pt);
            s_p += pb[j];
            s_t += tb[j];
        }
    }

    // 64-lane wave reduction
    #pragma unroll
    for (int off = 32; off; off >>= 1) {
        s_pt += __shfl_down(s_pt, off);
        s_p  += __shfl_down(s_p,  off);
        s_t  += __shfl_down(s_t,  off);
    }

    __shared__ float red[4][4];   // 4 waves x {pt,p,t}
    const int lane = threadIdx.x & 63;
    const int wid  = threadIdx.x >> 6;
    if (lane == 0) {
        red[wid][0] = s_pt;
        red[wid][1] = s_p;
        red[wid][2] = s_t;
    }
    __syncthreads();
    if (threadIdx.x == 0) {
        double a_pt = 0.0, a_p = 0.0, a_t = 0.0;
        #pragma unroll
        for (int k = 0; k < 4; ++k) {
            a_pt += (double)red[k][0];
            a_p  += (double)red[k][1];
            a_t  += (double)red[k][2];
        }
        atomicAdd(&acc[0],  a_pt);
        atomicAdd(&acc[8],  a_p);
        atomicAdd(&acc[16], a_t);
    }
}

__global__ void bl_final(const double* __restrict__ acc, float* __restrict__ out) {
    const double I = acc[0];
    const double P = acc[8];
    const double T = acc[16];
    const double dice = (2.0 * I + 1e-5) / (P + T + 1e-5);
    out[0] = (float)(1.0 - dice);
}

extern "C" void kernel_launch(void* const* d_in, const int* in_sizes, int n_in,
                              void* d_out, int out_size, void* d_ws, size_t ws_size,
                              hipStream_t stream) {
    const float* pred   = (const float*)d_in[0];
    const float* target = (const float*)d_in[1];
    double* acc = (double*)d_ws;

    hipMemsetAsync(d_ws, 0, 17 * sizeof(double), stream);
    bl_main<<<NBLOCKS, TPB, 0, stream>>>(pred, target, acc);
    bl_final<<<1, 1, 0, stream>>>(acc, (float*)d_out);
}